// Round 4
// baseline (948.599 us; speedup 1.0000x reference)
//
#include <hip/hip_runtime.h>
#include <hip/hip_bf16.h>
#include <math.h>

// LinearSqrtCrossEntropyLoss: fused bf16 MFMA GEMM + online-softmax partials.
// R4 (= R3 resubmit after infra failure): 256x256 8-wave deep-pipelined GEMM
// (T1 XCD-swizzle + T2 st_16x32 LDS swizzle + T3/T4 counted-vmcnt 4-deep
// K-tile ring + T5 setprio).
#define IGNORE_INDEX (-100)
#define BB 2
#define SS 4096
#define MM (BB * SS)      // 8192 tokens (GEMM M)
#define DD 1024           // hidden (GEMM K)
#define VV 32000          // vocab (GEMM N)

#define BM2 256
#define BN2 256
#define BK2 32
#define NT (DD / BK2)                  // 32 K-tiles
#define TM_TILES (MM / BM2)            // 32
#define TN_TILES (VV / BN2)            // 125
#define NWG2 (TM_TILES * TN_TILES)     // 4000 (% 8 == 0)
#define NCHUNK (VV / 64)               // 500 column-chunks of 64 per token

typedef __attribute__((ext_vector_type(8))) short bf16x8;
typedef __attribute__((ext_vector_type(4))) float f32x4;

__device__ __forceinline__ void gload_lds16(const void* g, void* l) {
  // async global->LDS, 16B/lane; LDS dest is wave-uniform base + lane*16
  __builtin_amdgcn_global_load_lds((const __attribute__((address_space(1))) void*)g,
                                   (__attribute__((address_space(3))) void*)l,
                                   16, 0, 0);
}

__device__ __forceinline__ short f2bf(float f) {   // round-to-nearest-even
  unsigned u = __float_as_uint(f);
  u += 0x7fffu + ((u >> 16) & 1u);
  return (short)(u >> 16);
}
__device__ __forceinline__ float bf2f(short s) {
  return __uint_as_float(((unsigned)(unsigned short)s) << 16);
}

#define SBAR() { __builtin_amdgcn_s_barrier(); __builtin_amdgcn_sched_barrier(0); }
#define WAIT_LGKM0() { asm volatile("s_waitcnt lgkmcnt(0)" ::: "memory"); __builtin_amdgcn_sched_barrier(0); }
#define WAIT_VMC(N) { asm volatile("s_waitcnt vmcnt(" #N ")" ::: "memory"); __builtin_amdgcn_sched_barrier(0); }

// ---- K0: fp32 -> bf16 convert (vectorized) ----
__global__ void cvt_bf16_kernel(const float* __restrict__ src, short* __restrict__ dst, int n4) {
  int i = blockIdx.x * blockDim.x + threadIdx.x;
  if (i >= n4) return;
  const float4 f = ((const float4*)src)[i];
  short4 o;
  o.x = f2bf(f.x); o.y = f2bf(f.y); o.z = f2bf(f.z); o.w = f2bf(f.w);
  ((short4*)dst)[i] = o;
}

// ---- K0b: per-batch-row valid-token counts ----
__global__ void count_kernel(const int* __restrict__ tgt, float* __restrict__ counts) {
  __shared__ int red[256];
  int b = blockIdx.x;
  int c = 0;
  for (int s = threadIdx.x; s < SS; s += 256) c += (tgt[b * SS + s] != IGNORE_INDEX) ? 1 : 0;
  red[threadIdx.x] = c;
  __syncthreads();
  for (int off = 128; off > 0; off >>= 1) {
    if (threadIdx.x < off) red[threadIdx.x] += red[threadIdx.x + off];
    __syncthreads();
  }
  if (threadIdx.x == 0) counts[b] = (float)red[0];
}

// ---- helpers ----
__device__ __forceinline__ void read4(const short* p, bf16x8* r) {
#pragma unroll
  for (int i = 0; i < 4; ++i) r[i] = *(const bf16x8*)(p + i * 512);
}
__device__ __forceinline__ void mfma16(const bf16x8* a4, const bf16x8* b4, f32x4 (*acc4)[4]) {
#pragma unroll
  for (int m = 0; m < 4; ++m)
#pragma unroll
    for (int n = 0; n < 4; ++n)
      acc4[m][n] = __builtin_amdgcn_mfma_f32_16x16x32_bf16(a4[m], b4[n], acc4[m][n], 0, 0, 0);
}

// ---- K1: 256x256 bf16 MFMA GEMM, 4-deep K-tile ring, fused LSE partials ----
// LDS per matrix: 4 ring bufs x [256 rows][32 k] bf16 (16KB each).
// st_16x32 swizzle: element column k stored at k ^ (((row>>3)&1)<<4); applied
// via pre-swizzled GLOBAL source column (linear gload_lds dest, rule 21) and
// the same XOR on ds_read addresses.
__global__ __launch_bounds__(512, 2) void gemm_lse8_kernel(
    const short* __restrict__ A,      // [MM][DD] bf16 bits
    const short* __restrict__ W,      // [VV][DD] bf16 bits
    float2* __restrict__ partials) {  // [MM][NCHUNK]
  __shared__ short sA[4 * 8192];      // 64 KB
  __shared__ short sB[4 * 8192];      // 64 KB
  const int tid = threadIdx.x;
  const int lane = tid & 63;
  const int wid = tid >> 6;
  const int wr = wid >> 2;            // 0..1  (rows wr*128 .. +127)
  const int wc = wid & 3;             // 0..3  (cols wc*64 .. +63)

  // T1: XCD-bijective swizzle; each XCD owns 4 m-tiles (2MB A panel in L2),
  // W panel reused 4x per XCD.
  const int wg = blockIdx.x;
  const int local = wg >> 3;              // 0..499
  const int mt = (wg & 7) * 4 + (local & 3);
  const int nt = local >> 2;              // 0..124
  const int mbase = mt * BM2;
  const int nbase = nt * BN2;

  // staging: thread covers LDS elems [j*4096 + tid*8): row j*128+(tid>>2),
  // k (tid&3)*8; source column pre-swizzled (involution).
  const int srow = tid >> 2;
  const int skoff = ((tid & 3) << 3) ^ (((tid >> 5) & 1) << 4);
  const short* Asrc = A + (size_t)(mbase + srow) * DD + skoff;
  const short* Bsrc = W + (size_t)(nbase + srow) * DD + skoff;

  // fragment read offsets (elements): row stride 32, swizzled k
  const int fr = lane & 15;
  const int kk = ((lane >> 4) << 3) ^ (((lane >> 3) & 1) << 4);
  const int offA = (wr * 128 + fr) * 32 + kk;
  const int offB = (wc * 64 + fr) * 32 + kk;

  f32x4 acc[8][4] = {};
  bf16x8 a[4], b[4];

#define STAGE_AT(tt) { const int _so = ((tt) & 3) * 8192; \
    const short* _s = Asrc + (size_t)(tt) * BK2; \
    gload_lds16(_s, &sA[_so + tid * 8]); \
    gload_lds16(_s + (size_t)128 * DD, &sA[_so + 4096 + tid * 8]); }
#define STAGE_BT(tt) { const int _so = ((tt) & 3) * 8192; \
    const short* _s = Bsrc + (size_t)(tt) * BK2; \
    gload_lds16(_s, &sB[_so + tid * 8]); \
    gload_lds16(_s + (size_t)128 * DD, &sB[_so + 4096 + tid * 8]); }

  // prologue: stage tiles 0,1 (4 loads/thread/tile, in-order vmcnt ledger)
  STAGE_AT(0); STAGE_BT(0); STAGE_AT(1); STAGE_BT(1);
  WAIT_VMC(4);   // tile 0 landed (newest 4 outstanding = tile 1)
  SBAR();

  // tile body: 2 phases x {ds_reads, stage-half, barrier, lgkm0, prio, 16 MFMA, prio}
#define TILE(t, DOSTAGE) { \
    const int bufo = ((t) & 3) * 8192; \
    read4(&sA[bufo + offA], a); \
    read4(&sB[bufo + offB], b); \
    if (DOSTAGE) STAGE_AT((t) + 2); \
    SBAR(); WAIT_LGKM0(); \
    __builtin_amdgcn_s_setprio(1); mfma16(a, b, &acc[0]); __builtin_amdgcn_s_setprio(0); \
    SBAR(); \
    read4(&sA[bufo + offA + 2048], a); \
    if (DOSTAGE) STAGE_BT((t) + 2); \
    SBAR(); WAIT_LGKM0(); \
    __builtin_amdgcn_s_setprio(1); mfma16(a, b, &acc[4]); __builtin_amdgcn_s_setprio(0); \
  }

#pragma unroll 1
  for (int t = 0; t < NT - 2; ++t) {   // t = 0..29, stages t+2
    TILE(t, true);
    WAIT_VMC(4);    // newest 4 = tile t+2's loads => tile t+1 fully landed
    SBAR();
  }
  TILE(NT - 2, false);
  WAIT_VMC(0);      // last tile fully resident
  SBAR();
  TILE(NT - 1, false);

  // Epilogue: C/D layout col = lane&15, row = (lane>>4)*4 + i.
  const int chunk = nt * 4 + wc;
  const int rowg0 = mbase + wr * 128 + ((lane >> 4) << 2);
#pragma unroll
  for (int m = 0; m < 8; ++m) {
#pragma unroll
    for (int i = 0; i < 4; ++i) {
      float v = fmaxf(fmaxf(acc[m][0][i], acc[m][1][i]), fmaxf(acc[m][2][i], acc[m][3][i]));
#pragma unroll
      for (int off = 8; off >= 1; off >>= 1) v = fmaxf(v, __shfl_xor(v, off));
      float s = __expf(acc[m][0][i] - v) + __expf(acc[m][1][i] - v)
              + __expf(acc[m][2][i] - v) + __expf(acc[m][3][i] - v);
#pragma unroll
      for (int off = 8; off >= 1; off >>= 1) s += __shfl_xor(s, off);
      if ((lane & 15) == 0) {
        partials[(size_t)(rowg0 + m * 16 + i) * NCHUNK + chunk] = make_float2(v, s);
      }
    }
  }
}

// ---- K2: per-token finalize ----
__global__ void finalize_kernel(const short* __restrict__ A, const short* __restrict__ W,
                                const int* __restrict__ tgt,
                                const float2* __restrict__ partials,
                                const float* __restrict__ counts,
                                float2* __restrict__ tokres) {
  const int gtid = blockIdx.x * blockDim.x + threadIdx.x;
  const int t = gtid >> 6;
  const int lane = gtid & 63;
  if (t >= MM) return;
  const int target = tgt[t];

  float m = -INFINITY, Z = 0.f;
  const float2* p = partials + (size_t)t * NCHUNK;
  for (int c = lane; c < NCHUNK; c += 64) {
    float2 pc = p[c];
    if (pc.x > m) { Z = Z * __expf(m - pc.x) + pc.y; m = pc.x; }
    else          { Z += pc.y * __expf(pc.x - m); }
  }
#pragma unroll
  for (int off = 1; off < 64; off <<= 1) {
    float mo = __shfl_xor(m, off);
    float Zo = __shfl_xor(Z, off);
    float mn = fmaxf(m, mo);
    Z = Z * __expf(m - mn) + Zo * __expf(mo - mn);
    m = mn;
  }

  float dot = 0.f;
  if (target != IGNORE_INDEX) {
    const bf16x8* a8 = (const bf16x8*)(A + (size_t)t * DD) + lane * 2;
    const bf16x8* w8 = (const bf16x8*)(W + (size_t)target * DD) + lane * 2;
#pragma unroll
    for (int j = 0; j < 2; ++j) {
      bf16x8 av = a8[j], wv = w8[j];
#pragma unroll
      for (int e = 0; e < 8; ++e) dot += bf2f(av[e]) * bf2f(wv[e]);
    }
#pragma unroll
    for (int off = 1; off < 64; off <<= 1) dot += __shfl_xor(dot, off);
  }

  if (lane == 0) {
    float wl = 0.f, w = 0.f;
    if (target != IGNORE_INDEX) {
      float l = counts[t >> 12];          // t / SS
      w = 1.0f / sqrtf(l + 1e-8f);
      wl = (m + __logf(Z) - dot) * w;
    }
    tokres[t] = make_float2(wl, w);
  }
}

// ---- K3: deterministic final reduce -> scalar loss ----
__global__ void loss_reduce_kernel(const float2* __restrict__ tokres, float* __restrict__ out) {
  __shared__ float sl[256], sw[256];
  float l = 0.f, w = 0.f;
  for (int i = threadIdx.x; i < MM; i += 256) { float2 v = tokres[i]; l += v.x; w += v.y; }
  sl[threadIdx.x] = l; sw[threadIdx.x] = w;
  __syncthreads();
  for (int off = 128; off > 0; off >>= 1) {
    if (threadIdx.x < off) { sl[threadIdx.x] += sl[threadIdx.x + off]; sw[threadIdx.x] += sw[threadIdx.x + off]; }
    __syncthreads();
  }
  if (threadIdx.x == 0) out[0] = (sw[0] == 0.f) ? sl[0] : sl[0] / sw[0];
}

extern "C" void kernel_launch(void* const* d_in, const int* in_sizes, int n_in,
                              void* d_out, int out_size, void* d_ws, size_t ws_size,
                              hipStream_t stream) {
  const float* outputs = (const float*)d_in[0];  // [B,S,D] fp32
  const float* proj    = (const float*)d_in[1];  // [V,D]   fp32
  const int*   targets = (const int*)d_in[2];    // [B,S]   int32
  float* out = (float*)d_out;

  // workspace layout (~115.1 MB), all regions fully rewritten every call
  char* base = (char*)d_ws;
  short*  Abf      = (short*)base;                                         // 16.78 MB
  short*  Wbf      = (short*)(base + (size_t)MM * DD * 2);                 // 65.54 MB
  float2* partials = (float2*)(base + (size_t)MM * DD * 2 + (size_t)VV * DD * 2);  // 32.77 MB
  float*  counts   = (float*)((char*)partials + (size_t)MM * NCHUNK * 8);
  float2* tokres   = (float2*)((char*)counts + 256);                       // 64 KB

  cvt_bf16_kernel<<<(MM * DD / 4) / 256, 256, 0, stream>>>(outputs, Abf, MM * DD / 4);
  cvt_bf16_kernel<<<(VV * DD / 4) / 256, 256, 0, stream>>>(proj, Wbf, VV * DD / 4);
  count_kernel<<<BB, 256, 0, stream>>>(targets, counts);
  gemm_lse8_kernel<<<NWG2, 512, 0, stream>>>(Abf, Wbf, partials);
  finalize_kernel<<<(MM * 64) / 256, 256, 0, stream>>>(Abf, Wbf, targets, partials, counts, tokres);
  loss_reduce_kernel<<<1, 256, 0, stream>>>(tokres, out);
}